// Round 3
// baseline (19707.104 us; speedup 1.0000x reference)
//
#include <hip/hip_runtime.h>

// DeepLSTM on MI355X — persistent kernel (plain launch, 208 blocks, all co-resident),
// hand-rolled grid barrier, 1 barrier per timestep.
// Superstep s: layer1 computes t=s, layer2 computes t=s-1, head computes t=s-2.
// I/O is FP32 (per reference). Weights + x are converted once to bf16 in d_ws by
// prep kernels; gate GEMMs run on bf16 MFMA with fp32 accumulate; biases/output fp32.

typedef __attribute__((ext_vector_type(8))) short short8;
typedef __attribute__((ext_vector_type(16))) float f32x16;
typedef __attribute__((ext_vector_type(4))) float f32x4;

#define Tn 256
#define Bn 64
#define In 256
#define Hn 1024
#define On 256
#define SP 136            // LDS act row stride (elems) for 128-col chunks; 272B rows, 16B-aligned
#define NL1 64            // layer-1 blocks: 16 h-outputs each (64 packed gate rows)
#define NL2 128           // layer-2 blocks: 8 h-outputs each (32 packed gate rows)
#define NY  16            // head blocks: 16 output cols each
#define NBLK (NL1 + NL2 + NY)   // 208
#define CHUNK_B 17408     // 64*SP*2 bytes per LDS act chunk (128 K-cols)
#define SMEM_SZ 55808     // 2*CHUNK_B + 16896 (gate xchg) + 4096 (cell state) < 64 KiB
#define BHe 65536         // elements per h slab (64*1024)

// d_ws layout (all 16B-aligned)
#define WS_WIH1 0
#define WS_WHH1 2097152
#define WS_WIH2 10485760
#define WS_WHH2 20971520
#define WS_WL   29360128
#define WS_X    30015488
#define WS_H1   38404096
#define WS_H2   38666240
#define WS_ARR  38928384

static __device__ __forceinline__ unsigned short f2b(float f) {
  union { float f; unsigned int i; } v; v.f = f;
  unsigned int u = v.i;
  return (unsigned short)((u + 0x7FFFu + ((u >> 16) & 1u)) >> 16);  // RNE
}
static __device__ __forceinline__ float sigm(float x) { return 1.0f / (1.0f + __expf(-x)); }
static __device__ __forceinline__ float tanhf_(float x) {
  float ax = fabsf(x);
  float e = __expf(-2.0f * ax);
  return copysignf((1.0f - e) / (1.0f + e), x);   // NaN-safe for large |x|
}

__global__ void __launch_bounds__(256) cvt_bf16(const float* __restrict__ src,
                                                unsigned short* __restrict__ dst, int n4) {
  int i = blockIdx.x * blockDim.x + threadIdx.x;
  if (i >= n4) return;
  float4 v = ((const float4*)src)[i];
  ushort4 o;
  o.x = f2b(v.x); o.y = f2b(v.y); o.z = f2b(v.z); o.w = f2b(v.w);
  ((ushort4*)dst)[i] = o;
}

__global__ void __launch_bounds__(256) prep_zero(unsigned short* h1buf,
                                                 unsigned short* h2buf,
                                                 int* arrive) {
  int i = blockIdx.x * blockDim.x + threadIdx.x;   // 64 blocks * 256 = 16384 threads
  uint4 z = {0u, 0u, 0u, 0u};
  ((uint4*)h1buf)[i] = z;                          // 16384 * 16B = 262144 B (both parities)
  ((uint4*)h2buf)[i] = z;
  if (i < 256) arrive[i] = 0;
}

__global__ void __launch_bounds__(256, 1) lstm_persist(
    const unsigned short* __restrict__ x,     // bf16-converted [B][T][I]
    const unsigned short* __restrict__ Wih1, const unsigned short* __restrict__ Whh1,
    const float* __restrict__ bih1, const float* __restrict__ bhh1,
    const unsigned short* __restrict__ Wih2, const unsigned short* __restrict__ Whh2,
    const float* __restrict__ bih2, const float* __restrict__ bhh2,
    const unsigned short* __restrict__ Wl,  const float* __restrict__ bl,
    float* __restrict__ out,
    unsigned short* __restrict__ h1buf, unsigned short* __restrict__ h2buf,
    int* __restrict__ arrive)
{
  extern __shared__ char smem[];
  unsigned short* sbuf0 = (unsigned short*)smem;
  unsigned short* sbuf1 = (unsigned short*)(smem + CHUNK_B);
  float* sG = (float*)(smem + 2 * CHUNK_B);          // gate exchange (L1: 64x65, L2: 2x64x33)
  float* sc = (float*)(smem + 2 * CHUNK_B + 16896);  // cell state, fp32, LDS-resident

  const int tid = threadIdx.x;
  const int bid = blockIdx.x;
  const int lane = tid & 63;
  const int wid = tid >> 6;
  const int srow = tid >> 2;          // staging: row 0..63
  const int sseg = tid & 3;           // staging: 4 x uint4 (32 bf16) segment

  for (int e = tid; e < 1024; e += 256) sc[e] = 0.0f;  // c=0 at t=0

  for (int s = 0; s < Tn + 2; ++s) {
    // ---------------- layer 1: t = s ----------------
    if (bid < NL1) {
      if (s < Tn) {
        const int t = s;
        const unsigned short* h1rd = h1buf + ((s + 1) & 1) * BHe;  // h1(t-1)
        unsigned short* h1wr = h1buf + (s & 1) * BHe;              // h1(t)
        const int j0 = bid << 4;
        const int mtile = wid & 1, ntile = wid >> 1;
        const int arow = mtile * 32 + (lane & 31);
        const int brow = ntile * 32 + (lane & 31);
        const int gr = ((brow >> 4) << 10) + j0 + (brow & 15);     // global gate row
        const int hi8 = (lane >> 5) << 3;
        f32x16 acc0 = {}, acc1 = {}, acc2 = {}, acc3 = {};

        { // stage chunk 0 = x_t[:, 0:128]
          const uint4* s4 = (const uint4*)(x + ((size_t)srow * Tn + t) * In + sseg * 32);
          uint4* d4 = (uint4*)(sbuf0 + srow * SP + sseg * 32);
          #pragma unroll
          for (int j = 0; j < 4; ++j) d4[j] = s4[j];
        }
        __syncthreads();

        #pragma unroll
        for (int c = 0; c < 10; ++c) {
          unsigned short* cur = (c & 1) ? sbuf1 : sbuf0;
          unsigned short* nxt = (c & 1) ? sbuf0 : sbuf1;
          if (c < 9) { // stage chunk c+1
            int cc = c + 1;
            const unsigned short* src = (cc < 2)
                ? (x + ((size_t)srow * Tn + t) * In + cc * 128)
                : (h1rd + srow * Hn + (cc - 2) * 128);
            const uint4* s4 = (const uint4*)(src + sseg * 32);
            uint4* d4 = (uint4*)(nxt + srow * SP + sseg * 32);
            #pragma unroll
            for (int j = 0; j < 4; ++j) d4[j] = s4[j];
          }
          const unsigned short* ab = cur + arow * SP + hi8;
          const unsigned short* wb = (c < 2 ? Wih1 + (size_t)gr * In + c * 128
                                            : Whh1 + (size_t)gr * Hn + (c - 2) * 128) + hi8;
          #pragma unroll
          for (int kk = 0; kk < 128; kk += 64) {
            acc0 = __builtin_amdgcn_mfma_f32_32x32x16_bf16(*(const short8*)(ab + kk),      *(const short8*)(wb + kk),      acc0, 0, 0, 0);
            acc1 = __builtin_amdgcn_mfma_f32_32x32x16_bf16(*(const short8*)(ab + kk + 16), *(const short8*)(wb + kk + 16), acc1, 0, 0, 0);
            acc2 = __builtin_amdgcn_mfma_f32_32x32x16_bf16(*(const short8*)(ab + kk + 32), *(const short8*)(wb + kk + 32), acc2, 0, 0, 0);
            acc3 = __builtin_amdgcn_mfma_f32_32x32x16_bf16(*(const short8*)(ab + kk + 48), *(const short8*)(wb + kk + 48), acc3, 0, 0, 0);
          }
          __syncthreads();
        }

        f32x16 accv = (acc0 + acc1) + (acc2 + acc3);
        #pragma unroll
        for (int i = 0; i < 16; ++i) {  // C/D: col=lane&31, row=(reg&3)+8*(reg>>2)+4*(lane>>5)
          int rm = (i & 3) + ((i >> 2) << 3) + ((lane >> 5) << 2);
          int b = mtile * 32 + rm;
          sG[b * 65 + brow] = accv[i];
        }
        __syncthreads();
        #pragma unroll
        for (int e4 = 0; e4 < 4; ++e4) {
          int e = tid + e4 * 256;
          int b = e >> 4, o = e & 15;
          const float* gb = sG + b * 65;
          float ig = gb[o]      + bih1[j0 + o]        + bhh1[j0 + o];
          float fg = gb[16 + o] + bih1[1024 + j0 + o] + bhh1[1024 + j0 + o];
          float gg = gb[32 + o] + bih1[2048 + j0 + o] + bhh1[2048 + j0 + o];
          float og = gb[48 + o] + bih1[3072 + j0 + o] + bhh1[3072 + j0 + o];
          float cn = sigm(fg) * sc[e] + sigm(ig) * tanhf_(gg);
          sc[e] = cn;
          h1wr[b * Hn + j0 + o] = f2b(sigm(og) * tanhf_(cn));
        }
      }
    // ---------------- layer 2: t = s-1 ----------------
    } else if (bid < NL1 + NL2) {
      if (s >= 1 && s <= Tn) {
        const int t = s - 1;
        const unsigned short* h1rd = h1buf + ((s + 1) & 1) * BHe;  // h1(t)
        const unsigned short* h2rd = h2buf + (s & 1) * BHe;        // h2(t-1)
        unsigned short* h2wr = h2buf + ((s + 1) & 1) * BHe;        // h2(t)
        const int j0 = (bid - NL1) << 3;
        const int mtile = wid & 1, ks = wid >> 1;   // ks=0: chunks 0..9 (x,h1); ks=1: 10..17 (h2)
        const int arow = mtile * 32 + (lane & 31);
        const int brow = lane & 31;
        const int gr = ((brow >> 3) << 10) + j0 + (brow & 7);
        const int hi8 = (lane >> 5) << 3;
        f32x16 acc0 = {}, acc1 = {}, acc2 = {}, acc3 = {};

        { // stage chunk 0 = x_t[:, 0:128]
          const uint4* s4 = (const uint4*)(x + ((size_t)srow * Tn + t) * In + sseg * 32);
          uint4* d4 = (uint4*)(sbuf0 + srow * SP + sseg * 32);
          #pragma unroll
          for (int j = 0; j < 4; ++j) d4[j] = s4[j];
        }
        __syncthreads();

        #pragma unroll
        for (int c = 0; c < 18; ++c) {
          unsigned short* cur = (c & 1) ? sbuf1 : sbuf0;
          unsigned short* nxt = (c & 1) ? sbuf0 : sbuf1;
          if (c < 17) {
            int cc = c + 1;
            const unsigned short* src = (cc < 2)
                ? (x + ((size_t)srow * Tn + t) * In + cc * 128)
                : (cc < 10 ? (h1rd + srow * Hn + (cc - 2) * 128)
                           : (h2rd + srow * Hn + (cc - 10) * 128));
            const uint4* s4 = (const uint4*)(src + sseg * 32);
            uint4* d4 = (uint4*)(nxt + srow * SP + sseg * 32);
            #pragma unroll
            for (int j = 0; j < 4; ++j) d4[j] = s4[j];
          }
          bool active = (ks == 0) ? (c < 10) : (c >= 10);
          if (active) {
            const unsigned short* ab = cur + arow * SP + hi8;
            const unsigned short* wb = (ks == 0 ? Wih2 + (size_t)gr * 1280 + c * 128
                                                : Whh2 + (size_t)gr * Hn + (c - 10) * 128) + hi8;
            #pragma unroll
            for (int kk = 0; kk < 128; kk += 64) {
              acc0 = __builtin_amdgcn_mfma_f32_32x32x16_bf16(*(const short8*)(ab + kk),      *(const short8*)(wb + kk),      acc0, 0, 0, 0);
              acc1 = __builtin_amdgcn_mfma_f32_32x32x16_bf16(*(const short8*)(ab + kk + 16), *(const short8*)(wb + kk + 16), acc1, 0, 0, 0);
              acc2 = __builtin_amdgcn_mfma_f32_32x32x16_bf16(*(const short8*)(ab + kk + 32), *(const short8*)(wb + kk + 32), acc2, 0, 0, 0);
              acc3 = __builtin_amdgcn_mfma_f32_32x32x16_bf16(*(const short8*)(ab + kk + 48), *(const short8*)(wb + kk + 48), acc3, 0, 0, 0);
            }
          }
          __syncthreads();
        }

        f32x16 accv = (acc0 + acc1) + (acc2 + acc3);
        #pragma unroll
        for (int i = 0; i < 16; ++i) {
          int rm = (i & 3) + ((i >> 2) << 3) + ((lane >> 5) << 2);
          int b = mtile * 32 + rm;
          sG[ks * 2112 + b * 33 + brow] = accv[i];
        }
        __syncthreads();
        #pragma unroll
        for (int e2 = 0; e2 < 2; ++e2) {
          int e = tid + e2 * 256;
          int b = e >> 3, o = e & 7;
          const float* g0 = sG + b * 33;
          const float* g1 = sG + 2112 + b * 33;
          float ig = g0[o]      + g1[o]      + bih2[j0 + o]        + bhh2[j0 + o];
          float fg = g0[8 + o]  + g1[8 + o]  + bih2[1024 + j0 + o] + bhh2[1024 + j0 + o];
          float gg = g0[16 + o] + g1[16 + o] + bih2[2048 + j0 + o] + bhh2[2048 + j0 + o];
          float og = g0[24 + o] + g1[24 + o] + bih2[3072 + j0 + o] + bhh2[3072 + j0 + o];
          float cn = sigm(fg) * sc[e] + sigm(ig) * tanhf_(gg);
          sc[e] = cn;
          h2wr[b * Hn + j0 + o] = f2b(sigm(og) * tanhf_(cn));
        }
      }
    // ---------------- head: t = s-2 ----------------
    } else {
      if (s >= 2) {
        const int t = s - 2;
        const unsigned short* h2rd = h2buf + (s & 1) * BHe;   // h2(t)
        const int o0 = (bid - NL1 - NL2) << 4;
        const int quad = lane >> 4;
        const int l15 = lane & 15;
        const int hi8y = quad << 3;
        f32x4 acc0 = {}, acc1 = {};

        { // stage chunk 0 = x_t[:, 0:128]
          const uint4* s4 = (const uint4*)(x + ((size_t)srow * Tn + t) * In + sseg * 32);
          uint4* d4 = (uint4*)(sbuf0 + srow * SP + sseg * 32);
          #pragma unroll
          for (int j = 0; j < 4; ++j) d4[j] = s4[j];
        }
        __syncthreads();

        #pragma unroll
        for (int c = 0; c < 10; ++c) {
          unsigned short* cur = (c & 1) ? sbuf1 : sbuf0;
          unsigned short* nxt = (c & 1) ? sbuf0 : sbuf1;
          if (c < 9) {
            int cc = c + 1;
            const unsigned short* src = (cc < 2)
                ? (x + ((size_t)srow * Tn + t) * In + cc * 128)
                : (h2rd + srow * Hn + (cc - 2) * 128);
            const uint4* s4 = (const uint4*)(src + sseg * 32);
            uint4* d4 = (uint4*)(nxt + srow * SP + sseg * 32);
            #pragma unroll
            for (int j = 0; j < 4; ++j) d4[j] = s4[j];
          }
          const unsigned short* ab = cur + (wid * 16 + l15) * SP + hi8y;
          const unsigned short* wb = Wl + (size_t)(o0 + l15) * 1280 + c * 128 + hi8y;
          #pragma unroll
          for (int kk = 0; kk < 128; kk += 64) {
            acc0 = __builtin_amdgcn_mfma_f32_16x16x32_bf16(*(const short8*)(ab + kk),      *(const short8*)(wb + kk),      acc0, 0, 0, 0);
            acc1 = __builtin_amdgcn_mfma_f32_16x16x32_bf16(*(const short8*)(ab + kk + 32), *(const short8*)(wb + kk + 32), acc1, 0, 0, 0);
          }
          __syncthreads();
        }
        f32x4 accv = acc0 + acc1;
        float blv = bl[o0 + l15];
        #pragma unroll
        for (int i = 0; i < 4; ++i) {   // C/D 16x16: col=lane&15, row=(lane>>4)*4+reg
          int b = wid * 16 + quad * 4 + i;
          out[((size_t)b * Tn + t) * On + o0 + l15] = accv[i] + blv;
        }
      }
    }

    // ---------------- grid barrier (skip after final superstep) ----------------
    if (s < Tn + 1) {
      __threadfence();
      __syncthreads();
      if (tid == 0)
        __hip_atomic_store(&arrive[bid], s + 1, __ATOMIC_RELEASE, __HIP_MEMORY_SCOPE_AGENT);
      if (tid < 64) {
        const int tgt = s + 1;
        bool done = false;
        while (!done) {
          bool ok = true;
          #pragma unroll
          for (int j = 0; j < 4; ++j) {
            int idx = lane + j * 64;
            if (idx < NBLK) {
              int v = __hip_atomic_load(&arrive[idx], __ATOMIC_ACQUIRE, __HIP_MEMORY_SCOPE_AGENT);
              ok = ok && (v >= tgt);
            }
          }
          done = __all(ok);
        }
      }
      __threadfence();
      __syncthreads();
    }
  }
}

extern "C" void kernel_launch(void* const* d_in, const int* in_sizes, int n_in,
                              void* d_out, int out_size, void* d_ws, size_t ws_size,
                              hipStream_t stream) {
  (void)in_sizes; (void)n_in; (void)out_size; (void)ws_size;
  const float* xf    = (const float*)d_in[0];
  const float* Wih1f = (const float*)d_in[1];
  const float* Whh1f = (const float*)d_in[2];
  const float* bih1  = (const float*)d_in[3];
  const float* bhh1  = (const float*)d_in[4];
  const float* Wih2f = (const float*)d_in[5];
  const float* Whh2f = (const float*)d_in[6];
  const float* bih2  = (const float*)d_in[7];
  const float* bhh2  = (const float*)d_in[8];
  const float* Wlf   = (const float*)d_in[9];
  const float* bl    = (const float*)d_in[10];
  float* out = (float*)d_out;

  char* ws = (char*)d_ws;
  unsigned short* Wih1b = (unsigned short*)(ws + WS_WIH1);
  unsigned short* Whh1b = (unsigned short*)(ws + WS_WHH1);
  unsigned short* Wih2b = (unsigned short*)(ws + WS_WIH2);
  unsigned short* Whh2b = (unsigned short*)(ws + WS_WHH2);
  unsigned short* Wlb   = (unsigned short*)(ws + WS_WL);
  unsigned short* xb    = (unsigned short*)(ws + WS_X);
  unsigned short* h1buf = (unsigned short*)(ws + WS_H1);
  unsigned short* h2buf = (unsigned short*)(ws + WS_H2);
  int* arrive           = (int*)(ws + WS_ARR);

  // fp32 -> bf16 conversions (element counts / 4 per thread-quad)
  hipLaunchKernelGGL(cvt_bf16, dim3(1024), dim3(256), 0, stream, Wih1f, Wih1b, 262144);   // 4096x256
  hipLaunchKernelGGL(cvt_bf16, dim3(4096), dim3(256), 0, stream, Whh1f, Whh1b, 1048576);  // 4096x1024
  hipLaunchKernelGGL(cvt_bf16, dim3(5120), dim3(256), 0, stream, Wih2f, Wih2b, 1310720);  // 4096x1280
  hipLaunchKernelGGL(cvt_bf16, dim3(4096), dim3(256), 0, stream, Whh2f, Whh2b, 1048576);  // 4096x1024
  hipLaunchKernelGGL(cvt_bf16, dim3(320),  dim3(256), 0, stream, Wlf,   Wlb,   81920);    // 256x1280
  hipLaunchKernelGGL(cvt_bf16, dim3(4096), dim3(256), 0, stream, xf,    xb,    1048576);  // 64x256x256

  hipLaunchKernelGGL(prep_zero, dim3(64), dim3(256), 0, stream, h1buf, h2buf, arrive);

  hipLaunchKernelGGL(lstm_persist, dim3(NBLK), dim3(256), SMEM_SZ, stream,
                     xb, Wih1b, Whh1b, bih1, bhh1, Wih2b, Whh2b, bih2, bhh2, Wlb, bl,
                     out, h1buf, h2buf, arrive);
}

// Round 4
// 9943.035 us; speedup vs baseline: 1.9820x; 1.9820x over previous
//
#include <hip/hip_runtime.h>

// DeepLSTM on MI355X — persistent kernel (plain launch, 208 blocks, all co-resident),
// hand-rolled grid barrier, 1 barrier per timestep.
// Superstep s: layer1 computes t=s, layer2 computes t=s-1, head computes t=s-2.
// I/O is FP32. Weights + x converted once to bf16 in d_ws; gate GEMMs on bf16 MFMA.
// KEY (round 4): all cross-block data (h slabs, arrive flags) uses RELAXED agent-scope
// atomics only (sc1 L2-bypass, coherent via L3). No acquire/release/threadfence anywhere
// -> no buffer_inv / buffer_wbl2 -> weights stay L2-resident across all 256 steps.

typedef __attribute__((ext_vector_type(8))) short short8;
typedef __attribute__((ext_vector_type(16))) float f32x16;
typedef __attribute__((ext_vector_type(4))) float f32x4;

#define Tn 256
#define Bn 64
#define In 256
#define Hn 1024
#define On 256
#define SP 136            // LDS act row stride (elems) for 128-col chunks; 272B rows, 16B-aligned
#define NL1 64            // layer-1 blocks: 16 h-outputs each (64 packed gate rows)
#define NL2 128           // layer-2 blocks: 8 h-outputs each (32 packed gate rows)
#define NY  16            // head blocks: 16 output cols each
#define NBLK (NL1 + NL2 + NY)   // 208
#define CHUNK_B 17408     // 64*SP*2 bytes per LDS act chunk (128 K-cols)
#define SMEM_SZ 55808     // 2*CHUNK_B + 16896 (gate xchg) + 4096 (cell state) < 64 KiB
#define BHe 65536         // elements per h slab (64*1024)

// d_ws layout (all 16B-aligned)
#define WS_WIH1 0
#define WS_WHH1 2097152
#define WS_WIH2 10485760
#define WS_WHH2 20971520
#define WS_WL   29360128
#define WS_X    30015488
#define WS_H1   38404096
#define WS_H2   38666240
#define WS_ARR  38928384

static __device__ __forceinline__ unsigned short f2b(float f) {
  union { float f; unsigned int i; } v; v.f = f;
  unsigned int u = v.i;
  return (unsigned short)((u + 0x7FFFu + ((u >> 16) & 1u)) >> 16);  // RNE
}
static __device__ __forceinline__ float sigm(float x) { return 1.0f / (1.0f + __expf(-x)); }
static __device__ __forceinline__ float tanhf_(float x) {
  float ax = fabsf(x);
  float e = __expf(-2.0f * ax);
  return copysignf((1.0f - e) / (1.0f + e), x);   // NaN-safe for large |x|
}
// Relaxed agent-scope accessors: lower to global_load/store ... sc1 (L2-bypass, no cache inv)
static __device__ __forceinline__ unsigned long long ld64a(const void* p) {
  return __hip_atomic_load((const unsigned long long*)p, __ATOMIC_RELAXED, __HIP_MEMORY_SCOPE_AGENT);
}
static __device__ __forceinline__ void st32a(void* p, unsigned int v) {
  __hip_atomic_store((unsigned int*)p, v, __ATOMIC_RELAXED, __HIP_MEMORY_SCOPE_AGENT);
}
static __device__ __forceinline__ void st64a(void* p, unsigned long long v) {
  __hip_atomic_store((unsigned long long*)p, v, __ATOMIC_RELAXED, __HIP_MEMORY_SCOPE_AGENT);
}

__global__ void __launch_bounds__(256) cvt_bf16(const float* __restrict__ src,
                                                unsigned short* __restrict__ dst, int n4) {
  int i = blockIdx.x * blockDim.x + threadIdx.x;
  if (i >= n4) return;
  float4 v = ((const float4*)src)[i];
  ushort4 o;
  o.x = f2b(v.x); o.y = f2b(v.y); o.z = f2b(v.z); o.w = f2b(v.w);
  ((ushort4*)dst)[i] = o;
}

__global__ void __launch_bounds__(256) prep_zero(unsigned short* h1buf,
                                                 unsigned short* h2buf,
                                                 int* arrive) {
  int i = blockIdx.x * blockDim.x + threadIdx.x;   // 16384 threads
  // h slabs zeroed via relaxed agent atomics (keep them out of any L2 as dirty lines)
  st64a((unsigned long long*)h1buf + i, 0ull);
  st64a((unsigned long long*)h1buf + 16384 + i, 0ull);
  st64a((unsigned long long*)h2buf + i, 0ull);
  st64a((unsigned long long*)h2buf + 16384 + i, 0ull);
  if (i < 256) st32a(arrive + i, 0u);
}

__global__ void __launch_bounds__(256, 1) lstm_persist(
    const unsigned short* __restrict__ x,     // bf16-converted [B][T][I]
    const unsigned short* __restrict__ Wih1, const unsigned short* __restrict__ Whh1,
    const float* __restrict__ bih1, const float* __restrict__ bhh1,
    const unsigned short* __restrict__ Wih2, const unsigned short* __restrict__ Whh2,
    const float* __restrict__ bih2, const float* __restrict__ bhh2,
    const unsigned short* __restrict__ Wl,  const float* __restrict__ bl,
    float* __restrict__ out,
    unsigned short* __restrict__ h1buf, unsigned short* __restrict__ h2buf,
    int* __restrict__ arrive)
{
  extern __shared__ char smem[];
  unsigned short* sbuf0 = (unsigned short*)smem;
  unsigned short* sbuf1 = (unsigned short*)(smem + CHUNK_B);
  float* sG = (float*)(smem + 2 * CHUNK_B);          // gate exchange (L1: 64x65, L2: 2x64x33)
  float* sc = (float*)(smem + 2 * CHUNK_B + 16896);  // cell state, fp32, LDS-resident

  const int tid = threadIdx.x;
  const int bid = blockIdx.x;
  const int lane = tid & 63;
  const int wid = tid >> 6;
  const int srow = tid >> 2;          // staging: row 0..63
  const int sseg = tid & 3;           // staging: 64B segment per thread

  for (int e = tid; e < 1024; e += 256) sc[e] = 0.0f;  // c=0 at t=0

  for (int s = 0; s < Tn + 2; ++s) {
    // ---------------- layer 1: t = s ----------------
    if (bid < NL1) {
      if (s < Tn) {
        const int t = s;
        const unsigned short* h1rd = h1buf + ((s + 1) & 1) * BHe;  // h1(t-1)
        unsigned short* h1wr = h1buf + (s & 1) * BHe;              // h1(t)
        const int j0 = bid << 4;
        const int mtile = wid & 1, ntile = wid >> 1;
        const int arow = mtile * 32 + (lane & 31);
        const int brow = ntile * 32 + (lane & 31);
        const int gr = ((brow >> 4) << 10) + j0 + (brow & 15);     // global gate row
        const int hi8 = (lane >> 5) << 3;
        f32x16 acc0 = {}, acc1 = {}, acc2 = {}, acc3 = {};

        { // stage chunk 0 = x_t[:, 0:128] (x is private-read: normal cached loads)
          const uint4* s4 = (const uint4*)(x + ((size_t)srow * Tn + t) * In + sseg * 32);
          uint4* d4 = (uint4*)(sbuf0 + srow * SP + sseg * 32);
          #pragma unroll
          for (int j = 0; j < 4; ++j) d4[j] = s4[j];
        }
        __syncthreads();

        #pragma unroll
        for (int c = 0; c < 10; ++c) {
          unsigned short* cur = (c & 1) ? sbuf1 : sbuf0;
          unsigned short* nxt = (c & 1) ? sbuf0 : sbuf1;
          if (c < 9) { // stage chunk c+1
            int cc = c + 1;
            if (cc < 2) {
              const uint4* s4 = (const uint4*)(x + ((size_t)srow * Tn + t) * In + cc * 128 + sseg * 32);
              uint4* d4 = (uint4*)(nxt + srow * SP + sseg * 32);
              #pragma unroll
              for (int j = 0; j < 4; ++j) d4[j] = s4[j];
            } else { // h1(t-1): relaxed agent atomic loads (sc1)
              const unsigned short* src = h1rd + srow * Hn + (cc - 2) * 128 + sseg * 32;
              unsigned long long* d8 = (unsigned long long*)(nxt + srow * SP + sseg * 32);
              #pragma unroll
              for (int j = 0; j < 8; ++j) d8[j] = ld64a(src + j * 4);
            }
          }
          const unsigned short* ab = cur + arow * SP + hi8;
          const unsigned short* wb = (c < 2 ? Wih1 + (size_t)gr * In + c * 128
                                            : Whh1 + (size_t)gr * Hn + (c - 2) * 128) + hi8;
          #pragma unroll
          for (int kk = 0; kk < 128; kk += 64) {
            acc0 = __builtin_amdgcn_mfma_f32_32x32x16_bf16(*(const short8*)(ab + kk),      *(const short8*)(wb + kk),      acc0, 0, 0, 0);
            acc1 = __builtin_amdgcn_mfma_f32_32x32x16_bf16(*(const short8*)(ab + kk + 16), *(const short8*)(wb + kk + 16), acc1, 0, 0, 0);
            acc2 = __builtin_amdgcn_mfma_f32_32x32x16_bf16(*(const short8*)(ab + kk + 32), *(const short8*)(wb + kk + 32), acc2, 0, 0, 0);
            acc3 = __builtin_amdgcn_mfma_f32_32x32x16_bf16(*(const short8*)(ab + kk + 48), *(const short8*)(wb + kk + 48), acc3, 0, 0, 0);
          }
          __syncthreads();
        }

        f32x16 accv = (acc0 + acc1) + (acc2 + acc3);
        #pragma unroll
        for (int i = 0; i < 16; ++i) {  // C/D: col=lane&31, row=(reg&3)+8*(reg>>2)+4*(lane>>5)
          int rm = (i & 3) + ((i >> 2) << 3) + ((lane >> 5) << 2);
          int b = mtile * 32 + rm;
          sG[b * 65 + brow] = accv[i];
        }
        __syncthreads();
        #pragma unroll
        for (int p = 0; p < 2; ++p) {
          int pi = tid + p * 256;           // 0..511 : (batch b, col-pair op)
          int b = pi >> 3, op = (pi & 7) << 1;
          const float* gb = sG + b * 65;
          unsigned int pack = 0;
          #pragma unroll
          for (int k = 0; k < 2; ++k) {
            int o = op + k, e = b * 16 + o;
            float ig = gb[o]      + bih1[j0 + o]        + bhh1[j0 + o];
            float fg = gb[16 + o] + bih1[1024 + j0 + o] + bhh1[1024 + j0 + o];
            float gg = gb[32 + o] + bih1[2048 + j0 + o] + bhh1[2048 + j0 + o];
            float og = gb[48 + o] + bih1[3072 + j0 + o] + bhh1[3072 + j0 + o];
            float cn = sigm(fg) * sc[e] + sigm(ig) * tanhf_(gg);
            sc[e] = cn;
            pack |= ((unsigned int)f2b(sigm(og) * tanhf_(cn))) << (16 * k);
          }
          st32a(h1wr + b * Hn + j0 + op, pack);
        }
      }
    // ---------------- layer 2: t = s-1 ----------------
    } else if (bid < NL1 + NL2) {
      if (s >= 1 && s <= Tn) {
        const int t = s - 1;
        const unsigned short* h1rd = h1buf + ((s + 1) & 1) * BHe;  // h1(t)
        const unsigned short* h2rd = h2buf + (s & 1) * BHe;        // h2(t-1)
        unsigned short* h2wr = h2buf + ((s + 1) & 1) * BHe;        // h2(t)
        const int j0 = (bid - NL1) << 3;
        const int mtile = wid & 1, ks = wid >> 1;   // ks=0: chunks 0..9 (x,h1); ks=1: 10..17 (h2)
        const int arow = mtile * 32 + (lane & 31);
        const int brow = lane & 31;
        const int gr = ((brow >> 3) << 10) + j0 + (brow & 7);
        const int hi8 = (lane >> 5) << 3;
        f32x16 acc0 = {}, acc1 = {}, acc2 = {}, acc3 = {};

        { // stage chunk 0 = x_t[:, 0:128]
          const uint4* s4 = (const uint4*)(x + ((size_t)srow * Tn + t) * In + sseg * 32);
          uint4* d4 = (uint4*)(sbuf0 + srow * SP + sseg * 32);
          #pragma unroll
          for (int j = 0; j < 4; ++j) d4[j] = s4[j];
        }
        __syncthreads();

        #pragma unroll
        for (int c = 0; c < 18; ++c) {
          unsigned short* cur = (c & 1) ? sbuf1 : sbuf0;
          unsigned short* nxt = (c & 1) ? sbuf0 : sbuf1;
          if (c < 17) {
            int cc = c + 1;
            if (cc < 2) {
              const uint4* s4 = (const uint4*)(x + ((size_t)srow * Tn + t) * In + cc * 128 + sseg * 32);
              uint4* d4 = (uint4*)(nxt + srow * SP + sseg * 32);
              #pragma unroll
              for (int j = 0; j < 4; ++j) d4[j] = s4[j];
            } else { // h1(t) / h2(t-1): relaxed agent atomic loads (sc1)
              const unsigned short* src = (cc < 10) ? (h1rd + srow * Hn + (cc - 2) * 128)
                                                    : (h2rd + srow * Hn + (cc - 10) * 128);
              src += sseg * 32;
              unsigned long long* d8 = (unsigned long long*)(nxt + srow * SP + sseg * 32);
              #pragma unroll
              for (int j = 0; j < 8; ++j) d8[j] = ld64a(src + j * 4);
            }
          }
          bool active = (ks == 0) ? (c < 10) : (c >= 10);
          if (active) {
            const unsigned short* ab = cur + arow * SP + hi8;
            const unsigned short* wb = (ks == 0 ? Wih2 + (size_t)gr * 1280 + c * 128
                                                : Whh2 + (size_t)gr * Hn + (c - 10) * 128) + hi8;
            #pragma unroll
            for (int kk = 0; kk < 128; kk += 64) {
              acc0 = __builtin_amdgcn_mfma_f32_32x32x16_bf16(*(const short8*)(ab + kk),      *(const short8*)(wb + kk),      acc0, 0, 0, 0);
              acc1 = __builtin_amdgcn_mfma_f32_32x32x16_bf16(*(const short8*)(ab + kk + 16), *(const short8*)(wb + kk + 16), acc1, 0, 0, 0);
              acc2 = __builtin_amdgcn_mfma_f32_32x32x16_bf16(*(const short8*)(ab + kk + 32), *(const short8*)(wb + kk + 32), acc2, 0, 0, 0);
              acc3 = __builtin_amdgcn_mfma_f32_32x32x16_bf16(*(const short8*)(ab + kk + 48), *(const short8*)(wb + kk + 48), acc3, 0, 0, 0);
            }
          }
          __syncthreads();
        }

        f32x16 accv = (acc0 + acc1) + (acc2 + acc3);
        #pragma unroll
        for (int i = 0; i < 16; ++i) {
          int rm = (i & 3) + ((i >> 2) << 3) + ((lane >> 5) << 2);
          int b = mtile * 32 + rm;
          sG[ks * 2112 + b * 33 + brow] = accv[i];
        }
        __syncthreads();
        {
          int pi = tid;                      // 0..255 : (batch b, col-pair op)
          int b = pi >> 2, op = (pi & 3) << 1;
          const float* g0 = sG + b * 33;
          const float* g1 = sG + 2112 + b * 33;
          unsigned int pack = 0;
          #pragma unroll
          for (int k = 0; k < 2; ++k) {
            int o = op + k, e = b * 8 + o;
            float ig = g0[o]      + g1[o]      + bih2[j0 + o]        + bhh2[j0 + o];
            float fg = g0[8 + o]  + g1[8 + o]  + bih2[1024 + j0 + o] + bhh2[1024 + j0 + o];
            float gg = g0[16 + o] + g1[16 + o] + bih2[2048 + j0 + o] + bhh2[2048 + j0 + o];
            float og = g0[24 + o] + g1[24 + o] + bih2[3072 + j0 + o] + bhh2[3072 + j0 + o];
            float cn = sigm(fg) * sc[e] + sigm(ig) * tanhf_(gg);
            sc[e] = cn;
            pack |= ((unsigned int)f2b(sigm(og) * tanhf_(cn))) << (16 * k);
          }
          st32a(h2wr + b * Hn + j0 + op, pack);
        }
      }
    // ---------------- head: t = s-2 ----------------
    } else {
      if (s >= 2) {
        const int t = s - 2;
        const unsigned short* h2rd = h2buf + (s & 1) * BHe;   // h2(t)
        const int o0 = (bid - NL1 - NL2) << 4;
        const int quad = lane >> 4;
        const int l15 = lane & 15;
        const int hi8y = quad << 3;
        f32x4 acc0 = {}, acc1 = {};

        { // stage chunk 0 = x_t[:, 0:128]
          const uint4* s4 = (const uint4*)(x + ((size_t)srow * Tn + t) * In + sseg * 32);
          uint4* d4 = (uint4*)(sbuf0 + srow * SP + sseg * 32);
          #pragma unroll
          for (int j = 0; j < 4; ++j) d4[j] = s4[j];
        }
        __syncthreads();

        #pragma unroll
        for (int c = 0; c < 10; ++c) {
          unsigned short* cur = (c & 1) ? sbuf1 : sbuf0;
          unsigned short* nxt = (c & 1) ? sbuf0 : sbuf1;
          if (c < 9) {
            int cc = c + 1;
            if (cc < 2) {
              const uint4* s4 = (const uint4*)(x + ((size_t)srow * Tn + t) * In + cc * 128 + sseg * 32);
              uint4* d4 = (uint4*)(nxt + srow * SP + sseg * 32);
              #pragma unroll
              for (int j = 0; j < 4; ++j) d4[j] = s4[j];
            } else { // h2(t): relaxed agent atomic loads (sc1)
              const unsigned short* src = h2rd + srow * Hn + (cc - 2) * 128 + sseg * 32;
              unsigned long long* d8 = (unsigned long long*)(nxt + srow * SP + sseg * 32);
              #pragma unroll
              for (int j = 0; j < 8; ++j) d8[j] = ld64a(src + j * 4);
            }
          }
          const unsigned short* ab = cur + (wid * 16 + l15) * SP + hi8y;
          const unsigned short* wb = Wl + (size_t)(o0 + l15) * 1280 + c * 128 + hi8y;
          #pragma unroll
          for (int kk = 0; kk < 128; kk += 64) {
            acc0 = __builtin_amdgcn_mfma_f32_16x16x32_bf16(*(const short8*)(ab + kk),      *(const short8*)(wb + kk),      acc0, 0, 0, 0);
            acc1 = __builtin_amdgcn_mfma_f32_16x16x32_bf16(*(const short8*)(ab + kk + 32), *(const short8*)(wb + kk + 32), acc1, 0, 0, 0);
          }
          __syncthreads();
        }
        f32x4 accv = acc0 + acc1;
        float blv = bl[o0 + l15];
        #pragma unroll
        for (int i = 0; i < 4; ++i) {   // C/D 16x16: col=lane&15, row=(lane>>4)*4+reg
          int b = wid * 16 + quad * 4 + i;
          out[((size_t)b * Tn + t) * On + o0 + l15] = accv[i] + blv;
        }
      }
    }

    // ---------------- grid barrier (no fences: relaxed atomics + syncthreads only) ----------------
    if (s < Tn + 1) {
      __syncthreads();   // drains vmcnt(0) for all threads' sc1 stores before publishing
      if (tid == 0)
        __hip_atomic_store(&arrive[bid], s + 1, __ATOMIC_RELAXED, __HIP_MEMORY_SCOPE_AGENT);
      if (tid < 64) {
        const int tgt = s + 1;
        bool done = false;
        while (!done) {
          bool ok = true;
          #pragma unroll
          for (int j = 0; j < 4; ++j) {
            int idx = lane + j * 64;
            if (idx < NBLK) {
              int v = __hip_atomic_load(&arrive[idx], __ATOMIC_RELAXED, __HIP_MEMORY_SCOPE_AGENT);
              ok = ok && (v >= tgt);
            }
          }
          done = __all(ok);
        }
      }
      __syncthreads();
    }
  }
}

extern "C" void kernel_launch(void* const* d_in, const int* in_sizes, int n_in,
                              void* d_out, int out_size, void* d_ws, size_t ws_size,
                              hipStream_t stream) {
  (void)in_sizes; (void)n_in; (void)out_size; (void)ws_size;
  const float* xf    = (const float*)d_in[0];
  const float* Wih1f = (const float*)d_in[1];
  const float* Whh1f = (const float*)d_in[2];
  const float* bih1  = (const float*)d_in[3];
  const float* bhh1  = (const float*)d_in[4];
  const float* Wih2f = (const float*)d_in[5];
  const float* Whh2f = (const float*)d_in[6];
  const float* bih2  = (const float*)d_in[7];
  const float* bhh2  = (const float*)d_in[8];
  const float* Wlf   = (const float*)d_in[9];
  const float* bl    = (const float*)d_in[10];
  float* out = (float*)d_out;

  char* ws = (char*)d_ws;
  unsigned short* Wih1b = (unsigned short*)(ws + WS_WIH1);
  unsigned short* Whh1b = (unsigned short*)(ws + WS_WHH1);
  unsigned short* Wih2b = (unsigned short*)(ws + WS_WIH2);
  unsigned short* Whh2b = (unsigned short*)(ws + WS_WHH2);
  unsigned short* Wlb   = (unsigned short*)(ws + WS_WL);
  unsigned short* xb    = (unsigned short*)(ws + WS_X);
  unsigned short* h1buf = (unsigned short*)(ws + WS_H1);
  unsigned short* h2buf = (unsigned short*)(ws + WS_H2);
  int* arrive           = (int*)(ws + WS_ARR);

  // fp32 -> bf16 conversions (n4 = element count / 4)
  hipLaunchKernelGGL(cvt_bf16, dim3(1024), dim3(256), 0, stream, Wih1f, Wih1b, 262144);   // 4096x256
  hipLaunchKernelGGL(cvt_bf16, dim3(4096), dim3(256), 0, stream, Whh1f, Whh1b, 1048576);  // 4096x1024
  hipLaunchKernelGGL(cvt_bf16, dim3(5120), dim3(256), 0, stream, Wih2f, Wih2b, 1310720);  // 4096x1280
  hipLaunchKernelGGL(cvt_bf16, dim3(4096), dim3(256), 0, stream, Whh2f, Whh2b, 1048576);  // 4096x1024
  hipLaunchKernelGGL(cvt_bf16, dim3(320),  dim3(256), 0, stream, Wlf,   Wlb,   81920);    // 256x1280
  hipLaunchKernelGGL(cvt_bf16, dim3(4096), dim3(256), 0, stream, xf,    xb,    1048576);  // 64x256x256

  hipLaunchKernelGGL(prep_zero, dim3(64), dim3(256), 0, stream, h1buf, h2buf, arrive);

  hipLaunchKernelGGL(lstm_persist, dim3(NBLK), dim3(256), SMEM_SZ, stream,
                     xb, Wih1b, Whh1b, bih1, bhh1, Wih2b, Whh2b, bih2, bhh2, Wlb, bl,
                     out, h1buf, h2buf, arrive);
}

// Round 5
// 7446.512 us; speedup vs baseline: 2.6465x; 1.3353x over previous
//
#include <hip/hip_runtime.h>

// DeepLSTM on MI355X — persistent kernel (plain launch, 208 blocks = 1/CU, co-resident),
// hand-rolled grid barrier (relaxed agent atomics, no fences -> no L2 invalidation).
// ROUND 5: all weights live in VGPRs (preloaded once, ~320 regs/wave); per-step global
// traffic is only h-slab exchange (sc1/L3) + x staging (L2) + output stores.
// Superstep s: layer1 t=s, layer2 t=s-1, head t=s-2. I/O fp32; compute bf16 MFMA.

typedef __attribute__((ext_vector_type(8))) short short8;
typedef __attribute__((ext_vector_type(16))) float f32x16;
typedef __attribute__((ext_vector_type(4))) float f32x4;

#define Tn 256
#define In 256
#define Hn 1024
#define On 256
#define SP 136            // LDS act row stride (elems): 272B rows, 16B-aligned
#define NL1 64            // layer-1 blocks: 16 h-outputs each (64 gate rows)
#define NL2 128           // layer-2 blocks: 8 h-outputs each (32 gate rows)
#define NY  16            // head blocks: 16 output cols each
#define NBLK (NL1 + NL2 + NY)   // 208
#define CHUNK_B 17408     // 64*SP*2 bytes per LDS act chunk (128 K-cols)
#define SMEM_SZ 55808     // 2*CHUNK_B + 16896 (gate xchg) + 4096 (cell state)
#define BHe 65536         // elements per h slab (64*1024)

// d_ws layout
#define WS_WIH1 0
#define WS_WHH1 2097152
#define WS_WIH2 10485760
#define WS_WHH2 20971520
#define WS_WL   29360128
#define WS_X    30015488
#define WS_H1   38404096
#define WS_H2   38666240
#define WS_ARR  38928384

static __device__ __forceinline__ unsigned short f2b(float f) {
  union { float f; unsigned int i; } v; v.f = f;
  unsigned int u = v.i;
  return (unsigned short)((u + 0x7FFFu + ((u >> 16) & 1u)) >> 16);  // RNE
}
static __device__ __forceinline__ float sigm(float x) { return 1.0f / (1.0f + __expf(-x)); }
static __device__ __forceinline__ float tanhf_(float x) {
  float ax = fabsf(x);
  float e = __expf(-2.0f * ax);
  return copysignf((1.0f - e) / (1.0f + e), x);
}
static __device__ __forceinline__ unsigned long long ld64a(const void* p) {
  return __hip_atomic_load((const unsigned long long*)p, __ATOMIC_RELAXED, __HIP_MEMORY_SCOPE_AGENT);
}
static __device__ __forceinline__ void st32a(void* p, unsigned int v) {
  __hip_atomic_store((unsigned int*)p, v, __ATOMIC_RELAXED, __HIP_MEMORY_SCOPE_AGENT);
}
static __device__ __forceinline__ void st64a(void* p, unsigned long long v) {
  __hip_atomic_store((unsigned long long*)p, v, __ATOMIC_RELAXED, __HIP_MEMORY_SCOPE_AGENT);
}

static __device__ __forceinline__ void grid_barrier(int* arrive, int bid, int tid,
                                                    int lane, int tgt) {
  __syncthreads();   // drains vmcnt(0): all sc1 h-stores complete before publish
  if (tid == 0)
    __hip_atomic_store(&arrive[bid], tgt, __ATOMIC_RELAXED, __HIP_MEMORY_SCOPE_AGENT);
  if (tid < 64) {
    bool done = false;
    while (!done) {
      bool ok = true;
      #pragma unroll
      for (int j = 0; j < 4; ++j) {
        int idx = lane + j * 64;
        if (idx < NBLK) {
          int v = __hip_atomic_load(&arrive[idx], __ATOMIC_RELAXED, __HIP_MEMORY_SCOPE_AGENT);
          ok = ok && (v >= tgt);
        }
      }
      done = __all(ok);
      if (!done) __builtin_amdgcn_s_sleep(1);   // throttle poll traffic
    }
  }
  __syncthreads();
}

// stage both 128-col x chunks for timestep t into sbuf0/sbuf1 (plain cached loads)
static __device__ __forceinline__ void stage_x2(const unsigned short* __restrict__ x, int t,
    unsigned short* sbuf0, unsigned short* sbuf1, int srow, int sseg) {
  const unsigned short* base = x + ((size_t)srow * Tn + t) * In + sseg * 32;
  uint4* d0 = (uint4*)(sbuf0 + srow * SP + sseg * 32);
  uint4* d1 = (uint4*)(sbuf1 + srow * SP + sseg * 32);
  #pragma unroll
  for (int j = 0; j < 4; ++j) d0[j] = ((const uint4*)base)[j];
  #pragma unroll
  for (int j = 0; j < 4; ++j) d1[j] = ((const uint4*)(base + 128))[j];
}
// stage one 128-col h chunk (relaxed agent atomics, sc1)
static __device__ __forceinline__ void stage_h(const unsigned short* hsrc, int col0,
    unsigned short* nxt, int srow, int sseg) {
  const unsigned short* src = hsrc + srow * Hn + col0 + sseg * 32;
  unsigned long long* d8 = (unsigned long long*)(nxt + srow * SP + sseg * 32);
  #pragma unroll
  for (int j = 0; j < 8; ++j) d8[j] = ld64a(src + j * 4);
}

__global__ void __launch_bounds__(256) cvt_bf16(const float* __restrict__ src,
                                                unsigned short* __restrict__ dst, int n4) {
  int i = blockIdx.x * blockDim.x + threadIdx.x;
  if (i >= n4) return;
  float4 v = ((const float4*)src)[i];
  ushort4 o;
  o.x = f2b(v.x); o.y = f2b(v.y); o.z = f2b(v.z); o.w = f2b(v.w);
  ((ushort4*)dst)[i] = o;
}

__global__ void __launch_bounds__(256) prep_zero(unsigned short* h1buf,
                                                 unsigned short* h2buf,
                                                 int* arrive) {
  int i = blockIdx.x * blockDim.x + threadIdx.x;   // 16384 threads
  st64a((unsigned long long*)h1buf + i, 0ull);
  st64a((unsigned long long*)h1buf + 16384 + i, 0ull);
  st64a((unsigned long long*)h2buf + i, 0ull);
  st64a((unsigned long long*)h2buf + 16384 + i, 0ull);
  if (i < 256) st32a(arrive + i, 0u);
}

__global__ void __launch_bounds__(256, 1) lstm_persist(
    const unsigned short* __restrict__ x,
    const unsigned short* __restrict__ Wih1, const unsigned short* __restrict__ Whh1,
    const float* __restrict__ bih1, const float* __restrict__ bhh1,
    const unsigned short* __restrict__ Wih2, const unsigned short* __restrict__ Whh2,
    const float* __restrict__ bih2, const float* __restrict__ bhh2,
    const unsigned short* __restrict__ Wl,  const float* __restrict__ bl,
    float* __restrict__ out,
    unsigned short* __restrict__ h1buf, unsigned short* __restrict__ h2buf,
    int* __restrict__ arrive)
{
  extern __shared__ char smem[];
  unsigned short* sbuf0 = (unsigned short*)smem;
  unsigned short* sbuf1 = (unsigned short*)(smem + CHUNK_B);
  float* sG = (float*)(smem + 2 * CHUNK_B);          // gate exchange
  float* sc = (float*)(smem + 2 * CHUNK_B + 16896);  // cell state (fp32)

  const int tid = threadIdx.x;
  const int bid = blockIdx.x;
  const int lane = tid & 63;
  const int wid = tid >> 6;
  const int srow = tid >> 2;
  const int sseg = tid & 3;

  for (int e = tid; e < 1024; e += 256) sc[e] = 0.0f;

  if (bid < NL1) {
    // =================== layer 1 ===================
    const int j0 = bid << 4;
    const int mtile = wid & 1, ntile = wid >> 1;
    const int arow = mtile * 32 + (lane & 31);
    const int brow = ntile * 32 + (lane & 31);
    const int gr = ((brow >> 4) << 10) + j0 + (brow & 15);
    const int hi8 = (lane >> 5) << 3;

    short8 w[80];                                     // 320 VGPRs: K=1280 weights
    #pragma unroll
    for (int c = 0; c < 10; ++c) {
      const unsigned short* wrow = (c < 2) ? (Wih1 + (size_t)gr * In + c * 128)
                                           : (Whh1 + (size_t)gr * Hn + (c - 2) * 128);
      #pragma unroll
      for (int k8 = 0; k8 < 8; ++k8)
        w[c * 8 + k8] = *(const short8*)(wrow + k8 * 16 + hi8);
    }
    float bs[2][2][4];                                // pre-summed biases
    #pragma unroll
    for (int p = 0; p < 2; ++p) {
      int pi = tid + p * 256, op = (pi & 7) << 1;
      #pragma unroll
      for (int k = 0; k < 2; ++k) {
        int o = op + k;
        #pragma unroll
        for (int g = 0; g < 4; ++g)
          bs[p][k][g] = bih1[g * 1024 + j0 + o] + bhh1[g * 1024 + j0 + o];
      }
    }

    stage_x2(x, 0, sbuf0, sbuf1, srow, sseg);
    __syncthreads();

    for (int s = 0; s < Tn; ++s) {
      const int t = s;
      const unsigned short* h1rd = h1buf + ((t + 1) & 1) * BHe;
      unsigned short* h1wr = h1buf + (t & 1) * BHe;
      f32x16 acc0 = {}, acc1 = {};

      #pragma unroll
      for (int c = 0; c < 10; ++c) {
        unsigned short* cur = (c & 1) ? sbuf1 : sbuf0;
        unsigned short* nxt = (c & 1) ? sbuf0 : sbuf1;
        int cc = c + 1;
        if (cc >= 2 && cc < 10) stage_h(h1rd, (cc - 2) * 128, nxt, srow, sseg);
        const unsigned short* ab = cur + arow * SP + hi8;
        #pragma unroll
        for (int k8 = 0; k8 < 8; k8 += 2) {
          acc0 = __builtin_amdgcn_mfma_f32_32x32x16_bf16(*(const short8*)(ab + k8 * 16),      w[c * 8 + k8],     acc0, 0, 0, 0);
          acc1 = __builtin_amdgcn_mfma_f32_32x32x16_bf16(*(const short8*)(ab + k8 * 16 + 16), w[c * 8 + k8 + 1], acc1, 0, 0, 0);
        }
        __syncthreads();
      }

      f32x16 accv = acc0 + acc1;
      #pragma unroll
      for (int i = 0; i < 16; ++i) {  // C/D: col=lane&31, row=(reg&3)+8*(reg>>2)+4*(lane>>5)
        int rm = (i & 3) + ((i >> 2) << 3) + ((lane >> 5) << 2);
        sG[(mtile * 32 + rm) * 65 + brow] = accv[i];
      }
      __syncthreads();

      if (t + 1 < Tn) stage_x2(x, t + 1, sbuf0, sbuf1, srow, sseg);  // prefetch next x

      #pragma unroll
      for (int p = 0; p < 2; ++p) {
        int pi = tid + p * 256;
        int b = pi >> 3, op = (pi & 7) << 1;
        const float* gb = sG + b * 65;
        unsigned int pack = 0;
        #pragma unroll
        for (int k = 0; k < 2; ++k) {
          int o = op + k, e = b * 16 + o;
          float ig = gb[o]      + bs[p][k][0];
          float fg = gb[16 + o] + bs[p][k][1];
          float gg = gb[32 + o] + bs[p][k][2];
          float og = gb[48 + o] + bs[p][k][3];
          float cn = sigm(fg) * sc[e] + sigm(ig) * tanhf_(gg);
          sc[e] = cn;
          pack |= ((unsigned int)f2b(sigm(og) * tanhf_(cn))) << (16 * k);
        }
        st32a(h1wr + b * Hn + j0 + op, pack);
      }
      grid_barrier(arrive, bid, tid, lane, s + 1);
    }
    grid_barrier(arrive, bid, tid, lane, Tn + 1);

  } else if (bid < NL1 + NL2) {
    // =================== layer 2 ===================
    const int j0 = (bid - NL1) << 3;
    const int mtile = wid & 1, ks = wid >> 1;   // ks=0: chunks 0..9 (x,h1); ks=1: 10..17 (h2)
    const int arow = mtile * 32 + (lane & 31);
    const int brow = lane & 31;
    const int gr = ((brow >> 3) << 10) + j0 + (brow & 7);
    const int hi8 = (lane >> 5) << 3;

    short8 w[80];                                     // ks=0: 80 used; ks=1: 64 used
    if (ks == 0) {
      #pragma unroll
      for (int c = 0; c < 10; ++c)
        #pragma unroll
        for (int k8 = 0; k8 < 8; ++k8)
          w[c * 8 + k8] = *(const short8*)(Wih2 + (size_t)gr * 1280 + c * 128 + k8 * 16 + hi8);
    } else {
      #pragma unroll
      for (int c = 0; c < 8; ++c)
        #pragma unroll
        for (int k8 = 0; k8 < 8; ++k8)
          w[c * 8 + k8] = *(const short8*)(Whh2 + (size_t)gr * Hn + c * 128 + k8 * 16 + hi8);
    }
    float bs[2][4];
    {
      int op = (tid & 3) << 1;
      #pragma unroll
      for (int k = 0; k < 2; ++k) {
        int o = op + k;
        #pragma unroll
        for (int g = 0; g < 4; ++g)
          bs[k][g] = bih2[g * 1024 + j0 + o] + bhh2[g * 1024 + j0 + o];
      }
    }

    stage_x2(x, 0, sbuf0, sbuf1, srow, sseg);
    grid_barrier(arrive, bid, tid, lane, 1);

    for (int s = 1; s <= Tn; ++s) {
      const int t = s - 1;
      const unsigned short* h1rd = h1buf + (t & 1) * BHe;        // h1(t)
      const unsigned short* h2rd = h2buf + ((t + 1) & 1) * BHe;  // h2(t-1)
      unsigned short* h2wr = h2buf + (t & 1) * BHe;              // h2(t)
      f32x16 acc0 = {}, acc1 = {};

      #pragma unroll
      for (int c = 0; c < 18; ++c) {
        unsigned short* cur = (c & 1) ? sbuf1 : sbuf0;
        unsigned short* nxt = (c & 1) ? sbuf0 : sbuf1;
        int cc = c + 1;
        if (cc >= 2 && cc < 18) {
          if (cc < 10) stage_h(h1rd, (cc - 2) * 128, nxt, srow, sseg);
          else         stage_h(h2rd, (cc - 10) * 128, nxt, srow, sseg);
        }
        bool active = (ks == 0) ? (c < 10) : (c >= 10);
        if (active) {
          int ib = ((ks == 0) ? c : (c - 10)) * 8;
          const unsigned short* ab = cur + arow * SP + hi8;
          #pragma unroll
          for (int k8 = 0; k8 < 8; k8 += 2) {
            acc0 = __builtin_amdgcn_mfma_f32_32x32x16_bf16(*(const short8*)(ab + k8 * 16),      w[ib + k8],     acc0, 0, 0, 0);
            acc1 = __builtin_amdgcn_mfma_f32_32x32x16_bf16(*(const short8*)(ab + k8 * 16 + 16), w[ib + k8 + 1], acc1, 0, 0, 0);
          }
        }
        __syncthreads();
      }

      f32x16 accv = acc0 + acc1;
      #pragma unroll
      for (int i = 0; i < 16; ++i) {
        int rm = (i & 3) + ((i >> 2) << 3) + ((lane >> 5) << 2);
        sG[ks * 2112 + (mtile * 32 + rm) * 33 + brow] = accv[i];
      }
      __syncthreads();

      if (t + 1 < Tn) stage_x2(x, t + 1, sbuf0, sbuf1, srow, sseg);

      {
        int b = tid >> 2, op = (tid & 3) << 1;
        const float* g0 = sG + b * 33;
        const float* g1 = sG + 2112 + b * 33;
        unsigned int pack = 0;
        #pragma unroll
        for (int k = 0; k < 2; ++k) {
          int o = op + k, e = b * 8 + o;
          float ig = g0[o]      + g1[o]      + bs[k][0];
          float fg = g0[8 + o]  + g1[8 + o]  + bs[k][1];
          float gg = g0[16 + o] + g1[16 + o] + bs[k][2];
          float og = g0[24 + o] + g1[24 + o] + bs[k][3];
          float cn = sigm(fg) * sc[e] + sigm(ig) * tanhf_(gg);
          sc[e] = cn;
          pack |= ((unsigned int)f2b(sigm(og) * tanhf_(cn))) << (16 * k);
        }
        st32a(h2wr + b * Hn + j0 + op, pack);
      }
      grid_barrier(arrive, bid, tid, lane, s + 1);
    }

  } else {
    // =================== head ===================
    const int o0 = (bid - NL1 - NL2) << 4;
    const int quad = lane >> 4;
    const int l15 = lane & 15;
    const int hi8y = quad << 3;

    short8 wy[40];                                    // 160 VGPRs: K=1280 head weights
    #pragma unroll
    for (int c = 0; c < 10; ++c)
      #pragma unroll
      for (int q = 0; q < 4; ++q)
        wy[c * 4 + q] = *(const short8*)(Wl + (size_t)(o0 + l15) * 1280 + c * 128 + q * 32 + hi8y);
    const float blv = bl[o0 + l15];

    stage_x2(x, 0, sbuf0, sbuf1, srow, sseg);
    grid_barrier(arrive, bid, tid, lane, 1);
    grid_barrier(arrive, bid, tid, lane, 2);

    for (int s = 2; s <= Tn + 1; ++s) {
      const int t = s - 2;
      const unsigned short* h2rd = h2buf + (t & 1) * BHe;   // h2(t)
      f32x4 acc0 = {}, acc1 = {};

      #pragma unroll
      for (int c = 0; c < 10; ++c) {
        unsigned short* cur = (c & 1) ? sbuf1 : sbuf0;
        unsigned short* nxt = (c & 1) ? sbuf0 : sbuf1;
        int cc = c + 1;
        if (cc >= 2 && cc < 10) stage_h(h2rd, (cc - 2) * 128, nxt, srow, sseg);
        const unsigned short* ab = cur + (wid * 16 + l15) * SP + hi8y;
        acc0 = __builtin_amdgcn_mfma_f32_16x16x32_bf16(*(const short8*)(ab),      wy[c * 4 + 0], acc0, 0, 0, 0);
        acc1 = __builtin_amdgcn_mfma_f32_16x16x32_bf16(*(const short8*)(ab + 32), wy[c * 4 + 1], acc1, 0, 0, 0);
        acc0 = __builtin_amdgcn_mfma_f32_16x16x32_bf16(*(const short8*)(ab + 64), wy[c * 4 + 2], acc0, 0, 0, 0);
        acc1 = __builtin_amdgcn_mfma_f32_16x16x32_bf16(*(const short8*)(ab + 96), wy[c * 4 + 3], acc1, 0, 0, 0);
        __syncthreads();
      }
      if (t + 1 < Tn) stage_x2(x, t + 1, sbuf0, sbuf1, srow, sseg);

      f32x4 accv = acc0 + acc1;
      #pragma unroll
      for (int i = 0; i < 4; ++i) {   // C/D 16x16: col=lane&15, row=(lane>>4)*4+reg
        int b = wid * 16 + quad * 4 + i;
        out[((size_t)b * Tn + t) * On + o0 + l15] = accv[i] + blv;
      }
      if (s <= Tn) grid_barrier(arrive, bid, tid, lane, s + 1);
    }
  }
}

extern "C" void kernel_launch(void* const* d_in, const int* in_sizes, int n_in,
                              void* d_out, int out_size, void* d_ws, size_t ws_size,
                              hipStream_t stream) {
  (void)in_sizes; (void)n_in; (void)out_size; (void)ws_size;
  const float* xf    = (const float*)d_in[0];
  const float* Wih1f = (const float*)d_in[1];
  const float* Whh1f = (const float*)d_in[2];
  const float* bih1  = (const float*)d_in[3];
  const float* bhh1  = (const float*)d_in[4];
  const float* Wih2f = (const float*)d_in[5];
  const float* Whh2f = (const float*)d_in[6];
  const float* bih2  = (const float*)d_in[7];
  const float* bhh2  = (const float*)d_in[8];
  const float* Wlf   = (const float*)d_in[9];
  const float* bl    = (const float*)d_in[10];
  float* out = (float*)d_out;

  char* ws = (char*)d_ws;
  unsigned short* Wih1b = (unsigned short*)(ws + WS_WIH1);
  unsigned short* Whh1b = (unsigned short*)(ws + WS_WHH1);
  unsigned short* Wih2b = (unsigned short*)(ws + WS_WIH2);
  unsigned short* Whh2b = (unsigned short*)(ws + WS_WHH2);
  unsigned short* Wlb   = (unsigned short*)(ws + WS_WL);
  unsigned short* xb    = (unsigned short*)(ws + WS_X);
  unsigned short* h1buf = (unsigned short*)(ws + WS_H1);
  unsigned short* h2buf = (unsigned short*)(ws + WS_H2);
  int* arrive           = (int*)(ws + WS_ARR);

  hipLaunchKernelGGL(cvt_bf16, dim3(1024), dim3(256), 0, stream, Wih1f, Wih1b, 262144);
  hipLaunchKernelGGL(cvt_bf16, dim3(4096), dim3(256), 0, stream, Whh1f, Whh1b, 1048576);
  hipLaunchKernelGGL(cvt_bf16, dim3(5120), dim3(256), 0, stream, Wih2f, Wih2b, 1310720);
  hipLaunchKernelGGL(cvt_bf16, dim3(4096), dim3(256), 0, stream, Whh2f, Whh2b, 1048576);
  hipLaunchKernelGGL(cvt_bf16, dim3(320),  dim3(256), 0, stream, Wlf,   Wlb,   81920);
  hipLaunchKernelGGL(cvt_bf16, dim3(4096), dim3(256), 0, stream, xf,    xb,    1048576);

  hipLaunchKernelGGL(prep_zero, dim3(64), dim3(256), 0, stream, h1buf, h2buf, arrive);

  hipLaunchKernelGGL(lstm_persist, dim3(NBLK), dim3(256), SMEM_SZ, stream,
                     xb, Wih1b, Whh1b, bih1, bhh1, Wih2b, Whh2b, bih2, bhh2, Wlb, bl,
                     out, h1buf, h2buf, arrive);
}

// Round 6
// 5360.946 us; speedup vs baseline: 3.6760x; 1.3890x over previous
//
#include <hip/hip_runtime.h>

// DeepLSTM on MI355X — persistent kernel (plain launch, 208 blocks, co-resident),
// relaxed-atomic grid barrier (no cache maintenance), weights persistent in VGPR/AGPR.
// ROUND 6: K-loop restructured as a software pipeline: global loads for chunk c+4
// issued at iter c into a register relay; per-chunk sync is raw s_barrier +
// lgkmcnt(0) only (NO vmcnt(0) drain), so sc1/L3 latency is covered by depth-4
// prefetch instead of being exposed 18x per step.

typedef __attribute__((ext_vector_type(8))) short short8;
typedef __attribute__((ext_vector_type(16))) float f32x16;
typedef __attribute__((ext_vector_type(4))) float f32x4;

#define Tn 256
#define In 256
#define Hn 1024
#define On 256
#define SP 136            // LDS act row stride (elems): 272B rows, 16B-aligned
#define NL1 64
#define NL2 128
#define NY  16
#define NBLK (NL1 + NL2 + NY)   // 208
#define CHUNK_B 17408     // 64*SP*2 bytes per LDS act chunk (128 K-cols)
#define SMEM_SZ 55808     // 2*CHUNK_B + 16896 (gate xchg) + 4096 (cell state)
#define BHe 65536

// d_ws layout
#define WS_WIH1 0
#define WS_WHH1 2097152
#define WS_WIH2 10485760
#define WS_WHH2 20971520
#define WS_WL   29360128
#define WS_X    30015488
#define WS_H1   38404096
#define WS_H2   38666240
#define WS_ARR  38928384

// s_waitcnt lgkmcnt(0), vmcnt/expcnt unconstrained (gfx9 encoding)
#define WAIT_LGKM0() __builtin_amdgcn_s_waitcnt(0xC07F)
#define RAW_BARRIER() do { \
    WAIT_LGKM0(); \
    __builtin_amdgcn_sched_barrier(0); \
    __builtin_amdgcn_s_barrier(); \
    __builtin_amdgcn_sched_barrier(0); \
  } while (0)

static __device__ __forceinline__ unsigned short f2b(float f) {
  union { float f; unsigned int i; } v; v.f = f;
  unsigned int u = v.i;
  return (unsigned short)((u + 0x7FFFu + ((u >> 16) & 1u)) >> 16);  // RNE
}
static __device__ __forceinline__ float sigm(float x) { return 1.0f / (1.0f + __expf(-x)); }
static __device__ __forceinline__ float tanhf_(float x) {
  float ax = fabsf(x);
  float e = __expf(-2.0f * ax);
  return copysignf((1.0f - e) / (1.0f + e), x);
}
static __device__ __forceinline__ unsigned long long ld64a(const void* p) {
  return __hip_atomic_load((const unsigned long long*)p, __ATOMIC_RELAXED, __HIP_MEMORY_SCOPE_AGENT);
}
static __device__ __forceinline__ void st32a(void* p, unsigned int v) {
  __hip_atomic_store((unsigned int*)p, v, __ATOMIC_RELAXED, __HIP_MEMORY_SCOPE_AGENT);
}
static __device__ __forceinline__ void st64a(void* p, unsigned long long v) {
  __hip_atomic_store((unsigned long long*)p, v, __ATOMIC_RELAXED, __HIP_MEMORY_SCOPE_AGENT);
}

static __device__ __forceinline__ void grid_barrier(int* arrive, int bid, int tid,
                                                    int lane, int tgt) {
  __syncthreads();   // full drain (vmcnt0): h-stores visible before publish
  if (tid == 0)
    __hip_atomic_store(&arrive[bid], tgt, __ATOMIC_RELAXED, __HIP_MEMORY_SCOPE_AGENT);
  if (tid < 64) {
    bool done = false;
    while (!done) {
      bool ok = true;
      #pragma unroll
      for (int j = 0; j < 4; ++j) {
        int idx = lane + j * 64;
        if (idx < NBLK) {
          int v = __hip_atomic_load(&arrive[idx], __ATOMIC_RELAXED, __HIP_MEMORY_SCOPE_AGENT);
          ok = ok && (v >= tgt);
        }
      }
      done = __all(ok);
      if (!done) __builtin_amdgcn_s_sleep(1);
    }
  }
  __syncthreads();
}

__global__ void __launch_bounds__(256) cvt_bf16(const float* __restrict__ src,
                                                unsigned short* __restrict__ dst, int n4) {
  int i = blockIdx.x * blockDim.x + threadIdx.x;
  if (i >= n4) return;
  float4 v = ((const float4*)src)[i];
  ushort4 o;
  o.x = f2b(v.x); o.y = f2b(v.y); o.z = f2b(v.z); o.w = f2b(v.w);
  ((ushort4*)dst)[i] = o;
}

__global__ void __launch_bounds__(256) prep_zero(unsigned short* h1buf,
                                                 unsigned short* h2buf,
                                                 int* arrive) {
  int i = blockIdx.x * blockDim.x + threadIdx.x;
  st64a((unsigned long long*)h1buf + i, 0ull);
  st64a((unsigned long long*)h1buf + 16384 + i, 0ull);
  st64a((unsigned long long*)h2buf + i, 0ull);
  st64a((unsigned long long*)h2buf + 16384 + i, 0ull);
  if (i < 256) st32a(arrive + i, 0u);
}

__global__ void __launch_bounds__(256, 1) lstm_persist(
    const unsigned short* __restrict__ x,
    const unsigned short* __restrict__ Wih1, const unsigned short* __restrict__ Whh1,
    const float* __restrict__ bih1, const float* __restrict__ bhh1,
    const unsigned short* __restrict__ Wih2, const unsigned short* __restrict__ Whh2,
    const float* __restrict__ bih2, const float* __restrict__ bhh2,
    const unsigned short* __restrict__ Wl,  const float* __restrict__ bl,
    float* __restrict__ out,
    unsigned short* __restrict__ h1buf, unsigned short* __restrict__ h2buf,
    int* __restrict__ arrive)
{
  extern __shared__ char smem[];
  unsigned short* sbuf0 = (unsigned short*)smem;
  unsigned short* sbuf1 = (unsigned short*)(smem + CHUNK_B);
  float* sG = (float*)(smem + 2 * CHUNK_B);
  float* sc = (float*)(smem + 2 * CHUNK_B + 16896);

  const int tid = threadIdx.x;
  const int bid = blockIdx.x;
  const int lane = tid & 63;
  const int wid = tid >> 6;
  const int srow = tid >> 2;          // staging row 0..63
  const int sseg = tid & 3;           // 64B segment within row

  for (int e = tid; e < 1024; e += 256) sc[e] = 0.0f;

  uint4 rs[4][4];                     // depth-4 relay: 64B/thread/chunk

  if (bid < NL1) {
    // =================== layer 1 ===================
    const int j0 = bid << 4;
    const int mtile = wid & 1, ntile = wid >> 1;
    const int arow = mtile * 32 + (lane & 31);
    const int brow = ntile * 32 + (lane & 31);
    const int gr = ((brow >> 4) << 10) + j0 + (brow & 15);
    const int hi8 = (lane >> 5) << 3;

    short8 w[80];
    #pragma unroll
    for (int c = 0; c < 10; ++c) {
      const unsigned short* wrow = (c < 2) ? (Wih1 + (size_t)gr * In + c * 128)
                                           : (Whh1 + (size_t)gr * Hn + (c - 2) * 128);
      #pragma unroll
      for (int k8 = 0; k8 < 8; ++k8)
        w[c * 8 + k8] = *(const short8*)(wrow + k8 * 16 + hi8);
    }
    float bs[2][2][4];
    #pragma unroll
    for (int p = 0; p < 2; ++p) {
      int pi = tid + p * 256, op = (pi & 7) << 1;
      #pragma unroll
      for (int k = 0; k < 2; ++k) {
        int o = op + k;
        #pragma unroll
        for (int g = 0; g < 4; ++g)
          bs[p][k][g] = bih1[g * 1024 + j0 + o] + bhh1[g * 1024 + j0 + o];
      }
    }

    for (int s = 0; s < Tn; ++s) {
      const int t = s;
      const unsigned short* h1rd = h1buf + ((t + 1) & 1) * BHe;
      unsigned short* h1wr = h1buf + (t & 1) * BHe;
      f32x16 acc0 = {}, acc1 = {};

      auto ldc = [&](int cc, int d) {
        if (cc < 2) {
          const uint4* s4 = (const uint4*)(x + ((size_t)srow * Tn + t) * In + cc * 128 + sseg * 32);
          #pragma unroll
          for (int j = 0; j < 4; ++j) rs[d][j] = s4[j];
        } else {
          const unsigned short* src = h1rd + srow * Hn + (cc - 2) * 128 + sseg * 32;
          #pragma unroll
          for (int j = 0; j < 4; ++j) {
            unsigned long long a = ld64a(src + j * 8);
            unsigned long long b = ld64a(src + j * 8 + 4);
            rs[d][j] = make_uint4((unsigned)a, (unsigned)(a >> 32), (unsigned)b, (unsigned)(b >> 32));
          }
        }
      };
      ldc(0, 0); ldc(1, 1); ldc(2, 2); ldc(3, 3);

      #pragma unroll
      for (int c = 0; c < 10; ++c) {
        unsigned short* buf = (c & 1) ? sbuf1 : sbuf0;
        {
          uint4* d4 = (uint4*)(buf + srow * SP + sseg * 32);
          #pragma unroll
          for (int j = 0; j < 4; ++j) d4[j] = rs[c & 3][j];
        }
        if (c + 4 < 10) ldc(c + 4, c & 3);
        RAW_BARRIER();
        const unsigned short* ab = buf + arow * SP + hi8;
        #pragma unroll
        for (int k8 = 0; k8 < 8; k8 += 2) {
          acc0 = __builtin_amdgcn_mfma_f32_32x32x16_bf16(*(const short8*)(ab + k8 * 16),      w[c * 8 + k8],     acc0, 0, 0, 0);
          acc1 = __builtin_amdgcn_mfma_f32_32x32x16_bf16(*(const short8*)(ab + k8 * 16 + 16), w[c * 8 + k8 + 1], acc1, 0, 0, 0);
        }
      }
      // one more raw barrier so last ds_reads complete before sG overwrite ordering below
      RAW_BARRIER();

      f32x16 accv = acc0 + acc1;
      #pragma unroll
      for (int i = 0; i < 16; ++i) {  // C/D: col=lane&31, row=(reg&3)+8*(reg>>2)+4*(lane>>5)
        int rm = (i & 3) + ((i >> 2) << 3) + ((lane >> 5) << 2);
        sG[(mtile * 32 + rm) * 65 + brow] = accv[i];
      }
      __syncthreads();

      #pragma unroll
      for (int p = 0; p < 2; ++p) {
        int pi = tid + p * 256;
        int b = pi >> 3, op = (pi & 7) << 1;
        const float* gb = sG + b * 65;
        unsigned int pack = 0;
        #pragma unroll
        for (int k = 0; k < 2; ++k) {
          int o = op + k, e = b * 16 + o;
          float ig = gb[o]      + bs[p][k][0];
          float fg = gb[16 + o] + bs[p][k][1];
          float gg = gb[32 + o] + bs[p][k][2];
          float og = gb[48 + o] + bs[p][k][3];
          float cn = sigm(fg) * sc[e] + sigm(ig) * tanhf_(gg);
          sc[e] = cn;
          pack |= ((unsigned int)f2b(sigm(og) * tanhf_(cn))) << (16 * k);
        }
        st32a(h1wr + b * Hn + j0 + op, pack);
      }
      grid_barrier(arrive, bid, tid, lane, s + 1);
    }
    grid_barrier(arrive, bid, tid, lane, Tn + 1);

  } else if (bid < NL1 + NL2) {
    // =================== layer 2 ===================
    const int j0 = (bid - NL1) << 3;
    const int mtile = wid & 1, ks = wid >> 1;
    const int arow = mtile * 32 + (lane & 31);
    const int brow = lane & 31;
    const int gr = ((brow >> 3) << 10) + j0 + (brow & 7);
    const int hi8 = (lane >> 5) << 3;

    short8 w[80];
    if (ks == 0) {
      #pragma unroll
      for (int c = 0; c < 10; ++c)
        #pragma unroll
        for (int k8 = 0; k8 < 8; ++k8)
          w[c * 8 + k8] = *(const short8*)(Wih2 + (size_t)gr * 1280 + c * 128 + k8 * 16 + hi8);
    } else {
      #pragma unroll
      for (int c = 0; c < 8; ++c)
        #pragma unroll
        for (int k8 = 0; k8 < 8; ++k8)
          w[c * 8 + k8] = *(const short8*)(Whh2 + (size_t)gr * Hn + c * 128 + k8 * 16 + hi8);
    }
    float bs[2][4];
    {
      int op = (tid & 3) << 1;
      #pragma unroll
      for (int k = 0; k < 2; ++k) {
        int o = op + k;
        #pragma unroll
        for (int g = 0; g < 4; ++g)
          bs[k][g] = bih2[g * 1024 + j0 + o] + bhh2[g * 1024 + j0 + o];
      }
    }

    grid_barrier(arrive, bid, tid, lane, 1);

    for (int s = 1; s <= Tn; ++s) {
      const int t = s - 1;
      const unsigned short* h1rd = h1buf + (t & 1) * BHe;        // h1(t)
      const unsigned short* h2rd = h2buf + ((t + 1) & 1) * BHe;  // h2(t-1)
      unsigned short* h2wr = h2buf + (t & 1) * BHe;              // h2(t)
      f32x16 acc0 = {}, acc1 = {};

      auto ldc = [&](int cc, int d) {
        if (cc < 2) {
          const uint4* s4 = (const uint4*)(x + ((size_t)srow * Tn + t) * In + cc * 128 + sseg * 32);
          #pragma unroll
          for (int j = 0; j < 4; ++j) rs[d][j] = s4[j];
        } else {
          const unsigned short* src = (cc < 10) ? (h1rd + srow * Hn + (cc - 2) * 128)
                                                : (h2rd + srow * Hn + (cc - 10) * 128);
          src += sseg * 32;
          #pragma unroll
          for (int j = 0; j < 4; ++j) {
            unsigned long long a = ld64a(src + j * 8);
            unsigned long long b = ld64a(src + j * 8 + 4);
            rs[d][j] = make_uint4((unsigned)a, (unsigned)(a >> 32), (unsigned)b, (unsigned)(b >> 32));
          }
        }
      };
      ldc(0, 0); ldc(1, 1); ldc(2, 2); ldc(3, 3);

      #pragma unroll
      for (int c = 0; c < 18; ++c) {
        unsigned short* buf = (c & 1) ? sbuf1 : sbuf0;
        {
          uint4* d4 = (uint4*)(buf + srow * SP + sseg * 32);
          #pragma unroll
          for (int j = 0; j < 4; ++j) d4[j] = rs[c & 3][j];
        }
        if (c + 4 < 18) ldc(c + 4, c & 3);
        RAW_BARRIER();
        bool active = (ks == 0) ? (c < 10) : (c >= 10);
        if (active) {
          int ib = ((ks == 0) ? c : (c - 10)) * 8;
          const unsigned short* ab = buf + arow * SP + hi8;
          #pragma unroll
          for (int k8 = 0; k8 < 8; k8 += 2) {
            acc0 = __builtin_amdgcn_mfma_f32_32x32x16_bf16(*(const short8*)(ab + k8 * 16),      w[ib + k8],     acc0, 0, 0, 0);
            acc1 = __builtin_amdgcn_mfma_f32_32x32x16_bf16(*(const short8*)(ab + k8 * 16 + 16), w[ib + k8 + 1], acc1, 0, 0, 0);
          }
        }
      }
      RAW_BARRIER();

      f32x16 accv = acc0 + acc1;
      #pragma unroll
      for (int i = 0; i < 16; ++i) {
        int rm = (i & 3) + ((i >> 2) << 3) + ((lane >> 5) << 2);
        sG[ks * 2112 + (mtile * 32 + rm) * 33 + brow] = accv[i];
      }
      __syncthreads();

      {
        int b = tid >> 2, op = (tid & 3) << 1;
        const float* g0 = sG + b * 33;
        const float* g1 = sG + 2112 + b * 33;
        unsigned int pack = 0;
        #pragma unroll
        for (int k = 0; k < 2; ++k) {
          int o = op + k, e = b * 8 + o;
          float ig = g0[o]      + g1[o]      + bs[k][0];
          float fg = g0[8 + o]  + g1[8 + o]  + bs[k][1];
          float gg = g0[16 + o] + g1[16 + o] + bs[k][2];
          float og = g0[24 + o] + g1[24 + o] + bs[k][3];
          float cn = sigm(fg) * sc[e] + sigm(ig) * tanhf_(gg);
          sc[e] = cn;
          pack |= ((unsigned int)f2b(sigm(og) * tanhf_(cn))) << (16 * k);
        }
        st32a(h2wr + b * Hn + j0 + op, pack);
      }
      grid_barrier(arrive, bid, tid, lane, s + 1);
    }

  } else {
    // =================== head ===================
    const int o0 = (bid - NL1 - NL2) << 4;
    const int quad = lane >> 4;
    const int l15 = lane & 15;
    const int hi8y = quad << 3;

    short8 wy[40];
    #pragma unroll
    for (int c = 0; c < 10; ++c)
      #pragma unroll
      for (int q = 0; q < 4; ++q)
        wy[c * 4 + q] = *(const short8*)(Wl + (size_t)(o0 + l15) * 1280 + c * 128 + q * 32 + hi8y);
    const float blv = bl[o0 + l15];

    grid_barrier(arrive, bid, tid, lane, 1);
    grid_barrier(arrive, bid, tid, lane, 2);

    for (int s = 2; s <= Tn + 1; ++s) {
      const int t = s - 2;
      const unsigned short* h2rd = h2buf + (t & 1) * BHe;   // h2(t)
      f32x4 acc0 = {}, acc1 = {};

      auto ldc = [&](int cc, int d) {
        if (cc < 2) {
          const uint4* s4 = (const uint4*)(x + ((size_t)srow * Tn + t) * In + cc * 128 + sseg * 32);
          #pragma unroll
          for (int j = 0; j < 4; ++j) rs[d][j] = s4[j];
        } else {
          const unsigned short* src = h2rd + srow * Hn + (cc - 2) * 128 + sseg * 32;
          #pragma unroll
          for (int j = 0; j < 4; ++j) {
            unsigned long long a = ld64a(src + j * 8);
            unsigned long long b = ld64a(src + j * 8 + 4);
            rs[d][j] = make_uint4((unsigned)a, (unsigned)(a >> 32), (unsigned)b, (unsigned)(b >> 32));
          }
        }
      };
      ldc(0, 0); ldc(1, 1); ldc(2, 2); ldc(3, 3);

      #pragma unroll
      for (int c = 0; c < 10; ++c) {
        unsigned short* buf = (c & 1) ? sbuf1 : sbuf0;
        {
          uint4* d4 = (uint4*)(buf + srow * SP + sseg * 32);
          #pragma unroll
          for (int j = 0; j < 4; ++j) d4[j] = rs[c & 3][j];
        }
        if (c + 4 < 10) ldc(c + 4, c & 3);
        RAW_BARRIER();
        const unsigned short* ab = buf + (wid * 16 + l15) * SP + hi8y;
        acc0 = __builtin_amdgcn_mfma_f32_16x16x32_bf16(*(const short8*)(ab),      wy[c * 4 + 0], acc0, 0, 0, 0);
        acc1 = __builtin_amdgcn_mfma_f32_16x16x32_bf16(*(const short8*)(ab + 32), wy[c * 4 + 1], acc1, 0, 0, 0);
        acc0 = __builtin_amdgcn_mfma_f32_16x16x32_bf16(*(const short8*)(ab + 64), wy[c * 4 + 2], acc0, 0, 0, 0);
        acc1 = __builtin_amdgcn_mfma_f32_16x16x32_bf16(*(const short8*)(ab + 96), wy[c * 4 + 3], acc1, 0, 0, 0);
      }
      RAW_BARRIER();

      f32x4 accv = acc0 + acc1;
      #pragma unroll
      for (int i = 0; i < 4; ++i) {   // C/D 16x16: col=lane&15, row=(lane>>4)*4+reg
        int b = wid * 16 + quad * 4 + i;
        out[((size_t)b * Tn + t) * On + o0 + l15] = accv[i] + blv;
      }
      if (s <= Tn) grid_barrier(arrive, bid, tid, lane, s + 1);
    }
  }
}

extern "C" void kernel_launch(void* const* d_in, const int* in_sizes, int n_in,
                              void* d_out, int out_size, void* d_ws, size_t ws_size,
                              hipStream_t stream) {
  (void)in_sizes; (void)n_in; (void)out_size; (void)ws_size;
  const float* xf    = (const float*)d_in[0];
  const float* Wih1f = (const float*)d_in[1];
  const float* Whh1f = (const float*)d_in[2];
  const float* bih1  = (const float*)d_in[3];
  const float* bhh1  = (const float*)d_in[4];
  const float* Wih2f = (const float*)d_in[5];
  const float* Whh2f = (const float*)d_in[6];
  const float* bih2  = (const float*)d_in[7];
  const float* bhh2  = (const float*)d_in[8];
  const float* Wlf   = (const float*)d_in[9];
  const float* bl    = (const float*)d_in[10];
  float* out = (float*)d_out;

  char* ws = (char*)d_ws;
  unsigned short* Wih1b = (unsigned short*)(ws + WS_WIH1);
  unsigned short* Whh1b = (unsigned short*)(ws + WS_WHH1);
  unsigned short* Wih2b = (unsigned short*)(ws + WS_WIH2);
  unsigned short* Whh2b = (unsigned short*)(ws + WS_WHH2);
  unsigned short* Wlb   = (unsigned short*)(ws + WS_WL);
  unsigned short* xb    = (unsigned short*)(ws + WS_X);
  unsigned short* h1buf = (unsigned short*)(ws + WS_H1);
  unsigned short* h2buf = (unsigned short*)(ws + WS_H2);
  int* arrive           = (int*)(ws + WS_ARR);

  hipLaunchKernelGGL(cvt_bf16, dim3(1024), dim3(256), 0, stream, Wih1f, Wih1b, 262144);
  hipLaunchKernelGGL(cvt_bf16, dim3(4096), dim3(256), 0, stream, Whh1f, Whh1b, 1048576);
  hipLaunchKernelGGL(cvt_bf16, dim3(5120), dim3(256), 0, stream, Wih2f, Wih2b, 1310720);
  hipLaunchKernelGGL(cvt_bf16, dim3(4096), dim3(256), 0, stream, Whh2f, Whh2b, 1048576);
  hipLaunchKernelGGL(cvt_bf16, dim3(320),  dim3(256), 0, stream, Wlf,   Wlb,   81920);
  hipLaunchKernelGGL(cvt_bf16, dim3(4096), dim3(256), 0, stream, xf,    xb,    1048576);

  hipLaunchKernelGGL(prep_zero, dim3(64), dim3(256), 0, stream, h1buf, h2buf, arrive);

  hipLaunchKernelGGL(lstm_persist, dim3(NBLK), dim3(256), SMEM_SZ, stream,
                     xb, Wih1b, Whh1b, bih1, bhh1, Wih2b, Whh2b, bih2, bhh2, Wlb, bl,
                     out, h1buf, h2buf, arrive);
}